// Round 10
// baseline (52.646 us; speedup 1.0000x reference)
//
#include <hip/hip_runtime.h>

typedef __attribute__((ext_vector_type(8))) short bf16x8;
typedef __attribute__((ext_vector_type(4))) float f32x4;

constexpr int TN = 8192;   // tokens
constexpr int DN = 4096;   // model dim
constexpr int EN = 64;     // experts

constexpr int BM = 16;         // rows per block
constexpr int NS = DN / 32;    // 128 MFMA K32 slots total
constexpr int NT = 16;         // slots per wave (64 per K-half / 4 waves)

__device__ __forceinline__ unsigned short f2bf(float f) {  // RNE f32->bf16
    unsigned u = __builtin_bit_cast(unsigned, f);
    u += 0x7FFFu + ((u >> 16) & 1u);
    return (unsigned short)(u >> 16);
}
__device__ __forceinline__ float bf2f(unsigned short h) {
    unsigned u = ((unsigned)h) << 16;
    return __builtin_bit_cast(float, u);
}

// Kernel 0: split wg into hi/lo bf16 planes in MFMA-fragment order:
// BF[p][s][et][lane*8+j] = plane_p( wg[et*16+(lane&15)][s*32+(lane>>4)*8+j] )
// so a wave's B-fragment load in the GEMM is base + lane*16B (1KB coalesced).
__global__ __launch_bounds__(256)
void wg_frag_kernel(const float* __restrict__ wg, unsigned short* __restrict__ BF) {
    const int gid = blockIdx.x * 256 + threadIdx.x;  // 65536 items
    const int l  = gid & 63;
    const int et = (gid >> 6) & 3;
    const int s  = (gid >> 8) & (NS - 1);
    const int p  = gid >> 15;
    const int e  = et * 16 + (l & 15);
    const int k  = s * 32 + (l >> 4) * 8;

    const float* src = wg + (size_t)e * DN + k;
    float4 v0 = *reinterpret_cast<const float4*>(src);
    float4 v1 = *reinterpret_cast<const float4*>(src + 4);
    float f[8] = {v0.x, v0.y, v0.z, v0.w, v1.x, v1.y, v1.z, v1.w};
    unsigned short o[8];
#pragma unroll
    for (int j = 0; j < 8; ++j) {
        unsigned short h = f2bf(f[j]);
        o[j] = p ? f2bf(f[j] - bf2f(h)) : h;
    }
    unsigned short* dst = BF + (((size_t)p * NS + s) * 4 + et) * 512 + (size_t)l * 8;
    *reinterpret_cast<ushort4*>(dst)     = make_ushort4(o[0], o[1], o[2], o[3]);
    *reinterpret_cast<ushort4*>(dst + 4) = make_ushort4(o[4], o[5], o[6], o[7]);
}

// Kernel 1: barrier-free direct-gather split-bf16 MFMA GEMM, K-split partials.
// Grid = 512 row-tiles x 2 K-halves = 1024 blocks (4/CU via
// __launch_bounds__(256,4), VGPR<=128 -> 16 waves/CU = 4 waves/SIMD).
// 4 waves; wave w owns K32 slots ks*64 + t*4 + w, t=0..15. A-fragments are
// loaded per-lane straight from global x (no LDS staging, no in-loop
// barriers) and split hi/lo in-register. A is depth-2 ping-pong; B is a
// single set, issued BEFORE the next A-prefetch so compute's B-wait
// (vmcnt(2)) leaves the A prefetch in flight. The B-wait (~L2 latency) is
// hidden by 4-wave/SIMD TLP. Note ks = bid&1 is invariant per XCD under
// round-robin dispatch -> each XCD's L2 holds only one 512KB B-half.
template <int KSPLIT>
__global__ __launch_bounds__(256, 4)
void gate_gemm_kernel(const float* __restrict__ x,
                      const unsigned short* __restrict__ BF,
                      float* __restrict__ part) {
    __shared__ float L[4][BM][68];      // 17408 B; per-wave partial logits

    const int tid  = threadIdx.x;
    const int lane = tid & 63;
    const int w    = tid >> 6;          // wave 0..3
    const int rt   = blockIdx.x >> (KSPLIT - 1);
    const int ks   = blockIdx.x & (KSPLIT - 1);
    const int r0   = rt * BM;
    const int sbase = ks * (NS / KSPLIT);

    const int fr  = lane & 15;          // fragment row (A) / expert col (B)
    const int fko = (lane >> 4) * 8;    // fragment k offset within K=32

    const float* xa = x + (size_t)(r0 + fr) * DN + fko;

    f32x4 acc[4] = {};                  // 4 expert tiles

    float4 XA0[2], XA1[2];              // ping-pong A fp32 (8 floats each)
    bf16x8 B[8];                        // single-set B ([et]=hi, [4+et]=lo)

    auto loadA = [&](float4 (&XA)[2], int t) {
        const float* p = xa + (size_t)(sbase + t * 4 + w) * 32;
        XA[0] = *reinterpret_cast<const float4*>(p);
        XA[1] = *reinterpret_cast<const float4*>(p + 4);
    };
    auto loadB = [&](int t) {
        const int s = sbase + t * 4 + w;
        const unsigned short* bp = BF + (size_t)s * 2048 + (size_t)lane * 8;
#pragma unroll
        for (int et = 0; et < 4; ++et)
            B[et] = *reinterpret_cast<const bf16x8*>(bp + et * 512);
#pragma unroll
        for (int et = 0; et < 4; ++et)
            B[4 + et] = *reinterpret_cast<const bf16x8*>(bp + (size_t)NS * 2048 + et * 512);
    };
    auto compute = [&](float4 (&XA)[2]) {
        float f[8] = {XA[0].x, XA[0].y, XA[0].z, XA[0].w,
                      XA[1].x, XA[1].y, XA[1].z, XA[1].w};
        bf16x8 ah, al;
#pragma unroll
        for (int j = 0; j < 8; ++j) {
            unsigned short hh = f2bf(f[j]);
            ah[j] = (short)hh;
            al[j] = (short)f2bf(f[j] - bf2f(hh));
        }
#pragma unroll
        for (int et = 0; et < 4; ++et) {
            acc[et] = __builtin_amdgcn_mfma_f32_16x16x32_bf16(ah, B[et],     acc[et], 0, 0, 0);
            acc[et] = __builtin_amdgcn_mfma_f32_16x16x32_bf16(al, B[et],     acc[et], 0, 0, 0);
            acc[et] = __builtin_amdgcn_mfma_f32_16x16x32_bf16(ah, B[4 + et], acc[et], 0, 0, 0);
            acc[et] = __builtin_amdgcn_mfma_f32_16x16x32_bf16(al, B[4 + et], acc[et], 0, 0, 0);
        }
    };

    // barrier-free pipeline: B(t) issued before A(t+1) so the B-wait keeps
    // the A prefetch in flight (FIFO vmcnt). A has a full iteration of slack.
    loadA(XA0, 0);
#pragma unroll 2
    for (int t = 0; t < NT; t += 2) {   // NT=16 even; static ping-pong (rule #20)
        loadB(t);
        if (t + 1 < NT) loadA(XA1, t + 1);
        asm volatile("" ::: "memory");
        compute(XA0);
        loadB(t + 1);
        if (t + 2 < NT) loadA(XA0, t + 2);
        asm volatile("" ::: "memory");
        compute(XA1);
    }

    // cross-wave k-slot reduction via LDS, coalesced partial store
#pragma unroll
    for (int et = 0; et < 4; ++et)
#pragma unroll
        for (int r = 0; r < 4; ++r)
            // C/D layout: col = lane&15, row = (lane>>4)*4 + reg  [m89]
            L[w][(lane >> 4) * 4 + r][et * 16 + fr] = acc[et][r];
    __syncthreads();

    {
        const int row = tid >> 4;       // 0..15
        const int eg  = tid & 15;       // 4 experts each
        float v[4];
#pragma unroll
        for (int j = 0; j < 4; ++j)
            v[j] = L[0][row][eg * 4 + j] + L[1][row][eg * 4 + j]
                 + L[2][row][eg * 4 + j] + L[3][row][eg * 4 + j];
        float* dst = part + ((size_t)ks * TN + r0 + row) * EN + eg * 4;
        *reinterpret_cast<float4*>(dst) = make_float4(v[0], v[1], v[2], v[3]);
    }
}

// Kernel 2: sum KSPLIT partials, top-1 softmax per row.
// out[0..TN) = argmax index (as float), out[TN..2TN) = max gate = 1/sumexp.
template <int NSPLIT>
__global__ __launch_bounds__(256)
void top1_softmax_kernel(const float* __restrict__ part, float* __restrict__ out) {
    const int row = blockIdx.x * blockDim.x + threadIdx.x;
    if (row >= TN) return;

    float v[EN];
#pragma unroll
    for (int i = 0; i < EN / 4; ++i) {
        float4 s = *reinterpret_cast<const float4*>(&part[(size_t)row * EN + i * 4]);
#pragma unroll
        for (int h = 1; h < NSPLIT; ++h) {
            float4 t = *reinterpret_cast<const float4*>(
                &part[((size_t)h * TN + row) * EN + i * 4]);
            s.x += t.x; s.y += t.y; s.z += t.z; s.w += t.w;
        }
        v[i * 4 + 0] = s.x; v[i * 4 + 1] = s.y;
        v[i * 4 + 2] = s.z; v[i * 4 + 3] = s.w;
    }

    float m = v[0];
    int idx = 0;
#pragma unroll
    for (int e = 1; e < EN; ++e)
        if (v[e] > m) { m = v[e]; idx = e; }  // strict >: first occurrence = jnp.argmax
    float s = 0.0f;
#pragma unroll
    for (int e = 0; e < EN; ++e) s += __expf(v[e] - m);

    out[row]      = (float)idx;
    out[TN + row] = 1.0f / s;
}

extern "C" void kernel_launch(void* const* d_in, const int* in_sizes, int n_in,
                              void* d_out, int out_size, void* d_ws, size_t ws_size,
                              hipStream_t stream) {
    const float* x  = (const float*)d_in[0];
    const float* wg = (const float*)d_in[1];
    float* out = (float*)d_out;

    constexpr size_t BF_BYTES = (size_t)2 * NS * 4 * 512 * 2;  // 1 MB
    unsigned short* BF = (unsigned short*)d_ws;
    float* part = (float*)((char*)d_ws + BF_BYTES);

    wg_frag_kernel<<<dim3(256), dim3(256), 0, stream>>>(wg, BF);

    const size_t need2 = BF_BYTES + (size_t)2 * TN * EN * sizeof(float);  // 5 MB
    if (ws_size >= need2) {
        gate_gemm_kernel<2><<<dim3(1024), dim3(256), 0, stream>>>(x, BF, part);
        top1_softmax_kernel<2><<<dim3(TN / 256), dim3(256), 0, stream>>>(part, out);
    } else {
        gate_gemm_kernel<1><<<dim3(512), dim3(256), 0, stream>>>(x, BF, part);
        top1_softmax_kernel<1><<<dim3(TN / 256), dim3(256), 0, stream>>>(part, out);
    }
}

// Round 11
// 38.038 us; speedup vs baseline: 1.3840x; 1.3840x over previous
//
#include <hip/hip_runtime.h>

typedef __attribute__((ext_vector_type(8))) short bf16x8;
typedef __attribute__((ext_vector_type(4))) float f32x4;

constexpr int TN = 8192;   // tokens
constexpr int DN = 4096;   // model dim
constexpr int EN = 64;     // experts

constexpr int BM = 32;         // rows per block
constexpr int NS = DN / 32;    // 128 MFMA K32 slots
constexpr int NT = 16;         // slots per wave (128 / 8 waves)

__device__ __forceinline__ unsigned short f2bf(float f) {  // RNE f32->bf16
    unsigned u = __builtin_bit_cast(unsigned, f);
    u += 0x7FFFu + ((u >> 16) & 1u);
    return (unsigned short)(u >> 16);
}
__device__ __forceinline__ float bf2f(unsigned short h) {
    unsigned u = ((unsigned)h) << 16;
    return __builtin_bit_cast(float, u);
}

// Kernel 0: split wg into hi/lo bf16 planes in MFMA-fragment order:
// BF[p][s][et][lane*8+j] = plane_p( wg[et*16+(lane&15)][s*32+(lane>>4)*8+j] )
// so a wave's B-fragment load in the GEMM is base + lane*16B (1KB coalesced).
__global__ __launch_bounds__(256)
void wg_frag_kernel(const float* __restrict__ wg, unsigned short* __restrict__ BF) {
    const int gid = blockIdx.x * 256 + threadIdx.x;  // 65536 items
    const int l  = gid & 63;
    const int et = (gid >> 6) & 3;
    const int s  = (gid >> 8) & (NS - 1);
    const int p  = gid >> 15;
    const int e  = et * 16 + (l & 15);
    const int k  = s * 32 + (l >> 4) * 8;

    const float* src = wg + (size_t)e * DN + k;
    float4 v0 = *reinterpret_cast<const float4*>(src);
    float4 v1 = *reinterpret_cast<const float4*>(src + 4);
    float f[8] = {v0.x, v0.y, v0.z, v0.w, v1.x, v1.y, v1.z, v1.w};
    unsigned short o[8];
#pragma unroll
    for (int j = 0; j < 8; ++j) {
        unsigned short h = f2bf(f[j]);
        o[j] = p ? f2bf(f[j] - bf2f(h)) : h;
    }
    unsigned short* dst = BF + (((size_t)p * NS + s) * 4 + et) * 512 + (size_t)l * 8;
    *reinterpret_cast<ushort4*>(dst)     = make_ushort4(o[0], o[1], o[2], o[3]);
    *reinterpret_cast<ushort4*>(dst + 4) = make_ushort4(o[4], o[5], o[6], o[7]);
}

// Kernel 1: barrier-free direct-gather split-bf16 MFMA GEMM + fused top-1.
// Grid = 256 blocks (1/CU), 512 threads = 8 INDEPENDENT waves (no in-loop
// __syncthreads). Wave w = (kq=w&3, kh=w>>2) owns K32 slots kh*64+t*4+kq,
// t=0..15, and computes both 16-row halves of the block's 32 rows (B regs
// shared across rows). A-fragments are loaded per-lane straight from global
// x (lanes fr,fr+16,fr+32,fr+48 jointly cover one 128B line of row fr) and
// split to hi/lo bf16 in-register. Pipeline: depth-3 on A (HBM ~900cyc ->
// ~2 compute-phases of slack), depth-2 on B (L2 ~300cyc -> 1 phase).
// Fully-unrolled loop: all buffer indices compile-time (rule #20).
__global__ __launch_bounds__(512, 2)
void gate_fused_kernel(const float* __restrict__ x,
                       const unsigned short* __restrict__ BF,
                       float* __restrict__ out) {
    __shared__ float L[8][BM][68];      // 69632 B; per-wave partial logits

    const int tid  = threadIdx.x;
    const int lane = tid & 63;
    const int w    = tid >> 6;          // wave 0..7
    const int kq   = w & 3;
    const int kh   = w >> 2;
    const int r0   = blockIdx.x * BM;

    const int fr  = lane & 15;          // fragment row (A) / expert col (B)
    const int fko = (lane >> 4) * 8;    // fragment k offset within K=32

    // per-lane A base: row r0+fr, +rh*16 rows, + s*32 + fko floats
    const float* xa = x + (size_t)(r0 + fr) * DN + fko;

    f32x4 acc[2][4] = {};               // [row-half][expert-tile]

    float4 XA[3][2][2];                 // depth-3 A fp32 ([set][rh][2x dwordx4])
    bf16x8 Bc[2][8];                    // depth-2 B ([set][et]=hi, [set][4+et]=lo)

    auto loadA = [&](float4 (&A)[2][2], int t) {
        const int s = kh * 64 + t * 4 + kq;
        const float* p = xa + s * 32;
#pragma unroll
        for (int rh = 0; rh < 2; ++rh) {
            const float* pr = p + (size_t)rh * 16 * DN;
            A[rh][0] = *reinterpret_cast<const float4*>(pr);
            A[rh][1] = *reinterpret_cast<const float4*>(pr + 4);
        }
    };
    auto loadB = [&](bf16x8 (&B)[8], int t) {
        const int s = kh * 64 + t * 4 + kq;
        const unsigned short* bp = BF + (size_t)s * 2048 + (size_t)lane * 8;
#pragma unroll
        for (int et = 0; et < 4; ++et)
            B[et] = *reinterpret_cast<const bf16x8*>(bp + et * 512);
#pragma unroll
        for (int et = 0; et < 4; ++et)
            B[4 + et] = *reinterpret_cast<const bf16x8*>(bp + (size_t)NS * 2048 + et * 512);
    };
    auto compute = [&](float4 (&A)[2][2], bf16x8 (&B)[8]) {
        bf16x8 ah[2], al[2];
#pragma unroll
        for (int rh = 0; rh < 2; ++rh) {
            float f[8] = {A[rh][0].x, A[rh][0].y, A[rh][0].z, A[rh][0].w,
                          A[rh][1].x, A[rh][1].y, A[rh][1].z, A[rh][1].w};
#pragma unroll
            for (int j = 0; j < 8; ++j) {
                unsigned short hh = f2bf(f[j]);
                ah[rh][j] = (short)hh;
                al[rh][j] = (short)f2bf(f[j] - bf2f(hh));
            }
        }
#pragma unroll
        for (int et = 0; et < 4; ++et)
#pragma unroll
            for (int rh = 0; rh < 2; ++rh) {
                acc[rh][et] = __builtin_amdgcn_mfma_f32_16x16x32_bf16(ah[rh], B[et],     acc[rh][et], 0, 0, 0);
                acc[rh][et] = __builtin_amdgcn_mfma_f32_16x16x32_bf16(al[rh], B[et],     acc[rh][et], 0, 0, 0);
                acc[rh][et] = __builtin_amdgcn_mfma_f32_16x16x32_bf16(ah[rh], B[4 + et], acc[rh][et], 0, 0, 0);
                acc[rh][et] = __builtin_amdgcn_mfma_f32_16x16x32_bf16(al[rh], B[4 + et], acc[rh][et], 0, 0, 0);
            }
    };

    // barrier-free pipeline: A depth-3, B depth-2. Loads for set k are
    // issued right after compute consumes set k (WAR safe: in-order issue).
    loadA(XA[0], 0);
    loadB(Bc[0], 0);
    loadA(XA[1], 1);
    loadB(Bc[1], 1);
    loadA(XA[2], 2);
#pragma unroll
    for (int t = 0; t < NT; ++t) {      // full unroll: t%3 / t%2 compile-time
        compute(XA[t % 3], Bc[t % 2]);
        if (t + 3 < NT) loadA(XA[t % 3], t + 3);
        if (t + 2 < NT) loadB(Bc[t % 2], t + 2);
        asm volatile("" ::: "memory");  // pin per-phase issue order
    }

    // epilogue: per-wave partial logits to LDS, then fused top-1 softmax
#pragma unroll
    for (int rh = 0; rh < 2; ++rh)
#pragma unroll
        for (int et = 0; et < 4; ++et)
#pragma unroll
            for (int r = 0; r < 4; ++r)
                // C/D layout: col = lane&15, row = (lane>>4)*4 + reg  [m89]
                L[w][rh * 16 + (lane >> 4) * 4 + r][et * 16 + fr] = acc[rh][et][r];
    __syncthreads();

    {
        const int row = tid >> 4;       // 0..31
        const int eg  = tid & 15;       // 4 experts each
        float v[4];
#pragma unroll
        for (int j = 0; j < 4; ++j) {
            float s = L[0][row][eg * 4 + j];
#pragma unroll
            for (int q = 1; q < 8; ++q) s += L[q][row][eg * 4 + j];
            v[j] = s;
        }
        float m = v[0];
        int idx = eg * 4;
#pragma unroll
        for (int j = 1; j < 4; ++j)
            if (v[j] > m) { m = v[j]; idx = eg * 4 + j; }  // strict >: first occurrence
#pragma unroll
        for (int d = 1; d < 16; d <<= 1) {
            float om = __shfl_xor(m, d);
            int   oi = __shfl_xor(idx, d);
            if (om > m || (om == m && oi < idx)) { m = om; idx = oi; }
        }
        float s = 0.0f;
#pragma unroll
        for (int j = 0; j < 4; ++j) s += __expf(v[j] - m);
#pragma unroll
        for (int d = 1; d < 16; d <<= 1) s += __shfl_xor(s, d);
        if (eg == 0) {
            out[r0 + row]      = (float)idx;     // argmax index
            out[TN + r0 + row] = 1.0f / s;       // max gate = 1/sum(exp(l-lmax))
        }
    }
}

extern "C" void kernel_launch(void* const* d_in, const int* in_sizes, int n_in,
                              void* d_out, int out_size, void* d_ws, size_t ws_size,
                              hipStream_t stream) {
    const float* x  = (const float*)d_in[0];
    const float* wg = (const float*)d_in[1];
    float* out = (float*)d_out;

    unsigned short* BF = (unsigned short*)d_ws;  // 1 MB fragment-ordered hi/lo

    wg_frag_kernel<<<dim3(256), dim3(256), 0, stream>>>(wg, BF);
    gate_fused_kernel<<<dim3(TN / BM), dim3(512), 0, stream>>>(x, BF, out);
}